// Round 4
// baseline (307.436 us; speedup 1.0000x reference)
//
#include <hip/hip_runtime.h>

// OFT rotation: out[n, r*64+c] = sum_k x[n, r*64+k] * R[r][k][c]
// R[r] = I + 2(Q + Q^2 + Q^3 + Q^4), Q skew-symmetric from strict-upper weights.

#define BS 64
#define NW 2016   // 64*63/2
#define LDP 68    // padded LDS row stride (build_R only)

typedef float vf4 __attribute__((ext_vector_type(4)));  // nt-store-compatible float4

// ---------------- Kernel 1: build R (64 blocks, one per rotation block) -------------
// UNCHANGED: known-good, bit-exact vs reference (absmax 0.0).

__device__ __forceinline__ void mm_tile_68(const float (*A)[LDP], const float (*Bm)[LDP],
                                           int r0, int c0, float p[4][4]) {
  for (int k = 0; k < 64; k += 4) {
    float4 bv[4], av[4];
#pragma unroll
    for (int u = 0; u < 4; ++u) bv[u] = *(const float4*)&Bm[k + u][c0];
#pragma unroll
    for (int i = 0; i < 4; ++i) av[i] = *(const float4*)&A[r0 + i][k];
#pragma unroll
    for (int u = 0; u < 4; ++u) {
      const float4 b = bv[u];
#pragma unroll
      for (int i = 0; i < 4; ++i) {
        const float a = ((const float*)&av[i])[u];
        p[i][0] += a * b.x;
        p[i][1] += a * b.y;
        p[i][2] += a * b.z;
        p[i][3] += a * b.w;
      }
    }
  }
}

__global__ __launch_bounds__(256) void oft_build_R(const float* __restrict__ w,
                                                   float* __restrict__ Rout) {
  const int r = blockIdx.x;
  const int t = threadIdx.x;
  __shared__ float Q[BS][LDP];
  __shared__ float Pa[BS][LDP];
  __shared__ float Pb[BS][LDP];

  for (int f = t; f < BS * LDP; f += 256) (&Q[0][0])[f] = 0.f;
  __syncthreads();

  for (int i = t; i < NW; i += 256) {
    int row = 0, rem = i;
    while (rem >= 63 - row) { rem -= 63 - row; ++row; }
    const int col = row + 1 + rem;
    const float v = w[r * NW + i];
    Q[row][col] = v;
    Q[col][row] = -v;
  }
  __syncthreads();

  const int tr = t >> 4, tc = t & 15;
  const int r0 = tr * 4, c0 = tc * 4;

  float acc[4][4];
#pragma unroll
  for (int i = 0; i < 4; ++i)
#pragma unroll
    for (int j = 0; j < 4; ++j)
      acc[i][j] = ((r0 + i) == (c0 + j) ? 1.f : 0.f) + 2.f * Q[r0 + i][c0 + j];

  float p[4][4] = {};
  mm_tile_68(Q, Q, r0, c0, p);
#pragma unroll
  for (int i = 0; i < 4; ++i)
#pragma unroll
    for (int j = 0; j < 4; ++j) {
      Pa[r0 + i][c0 + j] = p[i][j];
      acc[i][j] += 2.f * p[i][j];
    }
  __syncthreads();

  float p2[4][4] = {};
  mm_tile_68(Pa, Q, r0, c0, p2);
#pragma unroll
  for (int i = 0; i < 4; ++i)
#pragma unroll
    for (int j = 0; j < 4; ++j) {
      Pb[r0 + i][c0 + j] = p2[i][j];
      acc[i][j] += 2.f * p2[i][j];
    }
  __syncthreads();

  float p3[4][4] = {};
  mm_tile_68(Pb, Q, r0, c0, p3);
#pragma unroll
  for (int i = 0; i < 4; ++i)
#pragma unroll
    for (int j = 0; j < 4; ++j)
      acc[i][j] += 2.f * p3[i][j];

#pragma unroll
  for (int i = 0; i < 4; ++i) {
    float4 v = make_float4(acc[i][0], acc[i][1], acc[i][2], acc[i][3]);
    *(float4*)&Rout[(size_t)r * 4096 + (size_t)(r0 + i) * 64 + c0] = v;
  }
}

// ---------------- Kernel 2: apply rotation (v4b: lane=row, R via scalar path) -------
//
// History: v1 80us (LDS-bound, 1024 distinct b128 / 128 rows @ ~12cyc = 82us model);
// v2 236us (wave-uniform global loads, latency-bound); v3 92us (uniform LDS
// broadcasts still eat the LDS return path, 2048 instrs / 128 rows @ ~6cyc).
// Law: any scheme feeding <= 4 useful floats per LDS instr is LDS-pipe-bound ~3x
// over the 29us FMA floor.
//
// v4: lane = row. acc[64] = full output row in VGPRs (compile-time indices).
//   - x: per-lane own-row reads, 16 ds_read_b128 per wave per 64 rows (XOR-
//     swizzled -> conflict-free). LDS pipe ~400cyc/wave vs 8600 VALU: free.
//   - R: wave-uniform address -> s_load_dwordx16 via scalar K$ (R[r] = 16KB,
//     shared by all waves with same r). v_fmac v,s,v reads 1 SGPR: free.
//     s_load latency hidden by 256 fmac-cycles per k4 chunk + 2 waves/SIMD.
//   - out: transpose via the SAME wave-private 16KB LDS region (x dead, DS
//     in-order per wave) -> coalesced nt float4 stores. NO __syncthreads.
// k ascends (k4 outer, kk inner), single fma chain per output -> bit-identical.

__global__ __launch_bounds__(256) void oft_apply(const float* __restrict__ x,
                                                 const float* __restrict__ R,
                                                 float* __restrict__ out) {
  const int r = blockIdx.x;      // rotation block 0..63
  const int tile = blockIdx.y;   // 256-row tile 0..31
  const int t = threadIdx.x;
  const int lane = t & 63;
  const int wv = t >> 6;         // wave 0..3, owns rows [wv*64, wv*64+64)

  __shared__ float Xs[4][64 * 64];   // 16 KB per wave, wave-private (no syncs)
  float* __restrict__ Xw = &Xs[wv][0];

  const int n0 = tile * 256 + wv * 64;   // first row of this wave
  const float* __restrict__ xg = x + (size_t)n0 * 4096 + (size_t)r * 64;
  float* __restrict__ og = out + (size_t)n0 * 4096 + (size_t)r * 64;

  // ---- stage-in: 64 rows x 64 floats, coalesced global reads, swizzled LDS writes.
  // instr i: lanes 0-15 -> row 4i+0 (float4 j=0..15), lanes 16-31 -> row 4i+1, ...
  const int jj = lane & 15;          // float4 index within row
  const int rsub = lane >> 4;        // row sub-index 0..3
#pragma unroll
  for (int i = 0; i < 16; ++i) {
    const int row = i * 4 + rsub;
    const float4 v = *(const float4*)&xg[(size_t)row * 4096 + jj * 4];
    const int slot = jj ^ (row & 7);   // XOR swizzle: conflict-free row reads later
    *(float4*)&Xw[row * 64 + slot * 4] = v;
  }

  // ---- compute: acc[c] = sum_k x[myrow, k] * R[r][k][c], k ascending.
  float acc[64];
#pragma unroll
  for (int c = 0; c < 64; ++c) acc[c] = 0.f;

  const float* __restrict__ Rb = R + (size_t)r * 4096;   // wave-uniform base

  for (int k4 = 0; k4 < 16; ++k4) {
    const int slot = k4 ^ (lane & 7);
    const float4 xv = *(const float4*)&Xw[lane * 64 + slot * 4];  // own row, 4 k's
    const float xk[4] = {xv.x, xv.y, xv.z, xv.w};
#pragma unroll
    for (int kk = 0; kk < 4; ++kk) {
      const float a = xk[kk];
      const float* __restrict__ Rrow = Rb + (k4 * 4 + kk) * 64;  // uniform -> s_load
#pragma unroll
      for (int c = 0; c < 64; ++c)
        acc[c] = fmaf(a, Rrow[c], acc[c]);
    }
  }

  // ---- stage-out: write acc rows into the same wave-private LDS (swizzled),
  // then read back coalesced and nt-store. DS ops are in-order per wave; the
  // compiler inserts the lgkmcnt for the WAR on Xw.
#pragma unroll
  for (int c4 = 0; c4 < 16; ++c4) {
    const int slot = c4 ^ (lane & 7);
    float4 v = make_float4(acc[c4 * 4 + 0], acc[c4 * 4 + 1],
                           acc[c4 * 4 + 2], acc[c4 * 4 + 3]);
    *(float4*)&Xw[lane * 64 + slot * 4] = v;
  }
#pragma unroll
  for (int i = 0; i < 16; ++i) {
    const int row = i * 4 + rsub;
    const int slot = jj ^ (row & 7);
    const float4 v = *(const float4*)&Xw[row * 64 + slot * 4];
    // nt: keep the 134 MB output stream out of L3 so x stays resident.
    // __builtin_nontemporal_store needs a native clang vector, not HIP float4.
    vf4 nv;
    nv.x = v.x; nv.y = v.y; nv.z = v.z; nv.w = v.w;
    __builtin_nontemporal_store(nv, (vf4*)&og[(size_t)row * 4096 + jj * 4]);
  }
}

extern "C" void kernel_launch(void* const* d_in, const int* in_sizes, int n_in,
                              void* d_out, int out_size, void* d_ws, size_t ws_size,
                              hipStream_t stream) {
  const float* x = (const float*)d_in[0];   // (8192, 4096) fp32
  const float* w = (const float*)d_in[1];   // (64, 2016) fp32
  float* out = (float*)d_out;               // (8192, 4096) fp32
  float* Rws = (float*)d_ws;                // 64*64*64 fp32 = 1 MB scratch

  oft_build_R<<<64, 256, 0, stream>>>(w, Rws);
  oft_apply<<<dim3(64, 32), 256, 0, stream>>>(x, Rws, out);
}

// Round 5
// 272.631 us; speedup vs baseline: 1.1277x; 1.1277x over previous
//
#include <hip/hip_runtime.h>

// OFT rotation: out[n, r*64+c] = sum_k x[n, r*64+k] * R[r][k][c]
// R[r] = I + 2(Q + Q^2 + Q^3 + Q^4), Q skew-symmetric from strict-upper weights.

#define BS 64
#define NW 2016   // 64*63/2
#define LDP 68    // padded LDS row stride (build_R only)

typedef float vf4 __attribute__((ext_vector_type(4)));  // nt-store-compatible float4

// ---------------- Kernel 1: build R (64 blocks, one per rotation block) -------------
// UNCHANGED: known-good, bit-exact vs reference (absmax 0.0).

__device__ __forceinline__ void mm_tile_68(const float (*A)[LDP], const float (*Bm)[LDP],
                                           int r0, int c0, float p[4][4]) {
  for (int k = 0; k < 64; k += 4) {
    float4 bv[4], av[4];
#pragma unroll
    for (int u = 0; u < 4; ++u) bv[u] = *(const float4*)&Bm[k + u][c0];
#pragma unroll
    for (int i = 0; i < 4; ++i) av[i] = *(const float4*)&A[r0 + i][k];
#pragma unroll
    for (int u = 0; u < 4; ++u) {
      const float4 b = bv[u];
#pragma unroll
      for (int i = 0; i < 4; ++i) {
        const float a = ((const float*)&av[i])[u];
        p[i][0] += a * b.x;
        p[i][1] += a * b.y;
        p[i][2] += a * b.z;
        p[i][3] += a * b.w;
      }
    }
  }
}

__global__ __launch_bounds__(256) void oft_build_R(const float* __restrict__ w,
                                                   float* __restrict__ Rout) {
  const int r = blockIdx.x;
  const int t = threadIdx.x;
  __shared__ float Q[BS][LDP];
  __shared__ float Pa[BS][LDP];
  __shared__ float Pb[BS][LDP];

  for (int f = t; f < BS * LDP; f += 256) (&Q[0][0])[f] = 0.f;
  __syncthreads();

  for (int i = t; i < NW; i += 256) {
    int row = 0, rem = i;
    while (rem >= 63 - row) { rem -= 63 - row; ++row; }
    const int col = row + 1 + rem;
    const float v = w[r * NW + i];
    Q[row][col] = v;
    Q[col][row] = -v;
  }
  __syncthreads();

  const int tr = t >> 4, tc = t & 15;
  const int r0 = tr * 4, c0 = tc * 4;

  float acc[4][4];
#pragma unroll
  for (int i = 0; i < 4; ++i)
#pragma unroll
    for (int j = 0; j < 4; ++j)
      acc[i][j] = ((r0 + i) == (c0 + j) ? 1.f : 0.f) + 2.f * Q[r0 + i][c0 + j];

  float p[4][4] = {};
  mm_tile_68(Q, Q, r0, c0, p);
#pragma unroll
  for (int i = 0; i < 4; ++i)
#pragma unroll
    for (int j = 0; j < 4; ++j) {
      Pa[r0 + i][c0 + j] = p[i][j];
      acc[i][j] += 2.f * p[i][j];
    }
  __syncthreads();

  float p2[4][4] = {};
  mm_tile_68(Pa, Q, r0, c0, p2);
#pragma unroll
  for (int i = 0; i < 4; ++i)
#pragma unroll
    for (int j = 0; j < 4; ++j) {
      Pb[r0 + i][c0 + j] = p2[i][j];
      acc[i][j] += 2.f * p2[i][j];
    }
  __syncthreads();

  float p3[4][4] = {};
  mm_tile_68(Pb, Q, r0, c0, p3);
#pragma unroll
  for (int i = 0; i < 4; ++i)
#pragma unroll
    for (int j = 0; j < 4; ++j)
      acc[i][j] += 2.f * p3[i][j];

#pragma unroll
  for (int i = 0; i < 4; ++i) {
    float4 v = make_float4(acc[i][0], acc[i][1], acc[i][2], acc[i][3]);
    *(float4*)&Rout[(size_t)r * 4096 + (size_t)(r0 + i) * 64 + c0] = v;
  }
}

// ---------------- Kernel 2: apply rotation (v5: 8x8 reg tile, transposed-x LDS) -----
//
// Law (measured v1-v4): LDS-pipe cost ~12cyc per ds_read_b128 wave-instr per CU
// (85 B/cyc) => LDS time = 41us * (bytes/FMA). Uniform operands via SMEM/VMEM are
// latency-dead (v2: 236us, v4: 143us — OoO SMEM forces lgkmcnt(0) drains).
// v1 4x4 tile: 2 B/FMA -> 82us. v5 8x8 tile: per k per thread A 8 floats (2 b128
// from transposed Xt) + B 8 floats (2 b128 from Rs) = 64B / 64 FMA = 1 B/FMA ->
// 41us LDS-bound; VALU floor 27us and HBM 32us hide underneath.
//
//   - Xt[k][row] per-wave (16 KB), row-QUAD xor-swizzle slot=rq^(k&7): main-loop
//     A-reads 2-way bank (free, m136). Staged via in-register 4x4 transpose
//     (4 b128 global + 4 b128 LDS writes per slot, one-time).
//   - Rs[k*64+c] block-shared (16 KB): B-reads tc*8 stride -> 2-way (free).
//   - LDS 80 KB/block -> exactly 2 blocks/CU (8 waves, 2/SIMD).
//   - k ascending single fmaf chain per output -> bit-identical to reference.

__global__ __launch_bounds__(256) void oft_apply(const float* __restrict__ x,
                                                 const float* __restrict__ R,
                                                 float* __restrict__ out) {
  const int r = blockIdx.x;      // rotation block 0..63
  const int tile = blockIdx.y;   // 256-row tile 0..31
  const int t = threadIdx.x;
  const int lane = t & 63;
  const int wv = t >> 6;         // wave 0..3, owns rows [wv*64, wv*64+64)

  __shared__ float Rs[64 * 64];      // 16 KB, flat row-major
  __shared__ float Xt[4][64 * 64];   // 4 x 16 KB, per-wave TRANSPOSED x (k-major)

  const int n0 = tile * 256 + wv * 64;

  // ---- stage Rs: whole block, coalesced b128 ----
  {
    const float4* Rg = (const float4*)(R + (size_t)r * 4096);
    float4* Rs4 = (float4*)Rs;
#pragma unroll
    for (int i = 0; i < 4; ++i) Rs4[t + 256 * i] = Rg[t + 256 * i];
  }

  // ---- stage Xt[wv]: 64 rows x 64 k, transposed + quad-swizzled ----
  float* __restrict__ Xw = &Xt[wv][0];
  {
    const int rq = lane >> 2;        // row-quad 0..15
    const int kq0 = lane & 3;        // k-quad sub-index
    const float* xg = x + (size_t)n0 * 4096 + (size_t)r * 64;
#pragma unroll
    for (int i = 0; i < 4; ++i) {
      const int kq = kq0 + 4 * i;    // k-quad 0..15
      const float4 v0 = *(const float4*)&xg[(size_t)(rq * 4 + 0) * 4096 + kq * 4];
      const float4 v1 = *(const float4*)&xg[(size_t)(rq * 4 + 1) * 4096 + kq * 4];
      const float4 v2 = *(const float4*)&xg[(size_t)(rq * 4 + 2) * 4096 + kq * 4];
      const float4 v3 = *(const float4*)&xg[(size_t)(rq * 4 + 3) * 4096 + kq * 4];
      // 4x4 transpose in registers: w_c[d] = x[rq*4+d][kq*4+c]
      const float4 w0 = make_float4(v0.x, v1.x, v2.x, v3.x);
      const float4 w1 = make_float4(v0.y, v1.y, v2.y, v3.y);
      const float4 w2 = make_float4(v0.z, v1.z, v2.z, v3.z);
      const float4 w3 = make_float4(v0.w, v1.w, v2.w, v3.w);
#pragma unroll
      for (int c = 0; c < 4; ++c) {
        const int k = kq * 4 + c;
        const int slot = rq ^ (k & 7);           // quad swizzle
        const float4 wc = (c == 0) ? w0 : (c == 1) ? w1 : (c == 2) ? w2 : w3;
        *(float4*)&Xw[k * 64 + slot * 4] = wc;
      }
    }
  }
  __syncthreads();   // Rs (block-shared) ready; Xt is wave-private (in-order DS)

  // ---- main loop: 8x8 per-thread tile ----
  const int tr = lane >> 3;   // thread-row 0..7 -> rows tr*8..tr*8+7
  const int tc = lane & 7;    // thread-col 0..7 -> cols tc*8..tc*8+7

  float acc[8][8];
#pragma unroll
  for (int i = 0; i < 8; ++i)
#pragma unroll
    for (int j = 0; j < 8; ++j) acc[i][j] = 0.f;

  for (int k0 = 0; k0 < 64; k0 += 4) {
    float4 a[4][2], b[4][2];
#pragma unroll
    for (int u = 0; u < 4; ++u) {
      const int k = k0 + u;
      const int s0 = ((2 * tr + 0) ^ (k & 7)) * 4;   // quad 2tr   -> rows tr*8..+3
      const int s1 = ((2 * tr + 1) ^ (k & 7)) * 4;   // quad 2tr+1 -> rows tr*8+4..+7
      a[u][0] = *(const float4*)&Xw[k * 64 + s0];
      a[u][1] = *(const float4*)&Xw[k * 64 + s1];
      b[u][0] = *(const float4*)&Rs[k * 64 + tc * 8];
      b[u][1] = *(const float4*)&Rs[k * 64 + tc * 8 + 4];
    }
#pragma unroll
    for (int u = 0; u < 4; ++u) {
      const float av[8] = {a[u][0].x, a[u][0].y, a[u][0].z, a[u][0].w,
                           a[u][1].x, a[u][1].y, a[u][1].z, a[u][1].w};
      const float bv[8] = {b[u][0].x, b[u][0].y, b[u][0].z, b[u][0].w,
                           b[u][1].x, b[u][1].y, b[u][1].z, b[u][1].w};
#pragma unroll
      for (int i = 0; i < 8; ++i)
#pragma unroll
        for (int j = 0; j < 8; ++j)
          acc[i][j] = fmaf(av[i], bv[j], acc[i][j]);   // k ascending per output
    }
  }

  // ---- epilogue: direct coalesced-ish nt stores (8 rows x 2 float4 per thread) ----
  float* __restrict__ og = out + (size_t)(n0 + tr * 8) * 4096 + (size_t)r * 64 + tc * 8;
#pragma unroll
  for (int i = 0; i < 8; ++i) {
    vf4 lo, hi;
    lo.x = acc[i][0]; lo.y = acc[i][1]; lo.z = acc[i][2]; lo.w = acc[i][3];
    hi.x = acc[i][4]; hi.y = acc[i][5]; hi.z = acc[i][6]; hi.w = acc[i][7];
    __builtin_nontemporal_store(lo, (vf4*)&og[(size_t)i * 4096]);
    __builtin_nontemporal_store(hi, (vf4*)&og[(size_t)i * 4096 + 4]);
  }
}

extern "C" void kernel_launch(void* const* d_in, const int* in_sizes, int n_in,
                              void* d_out, int out_size, void* d_ws, size_t ws_size,
                              hipStream_t stream) {
  const float* x = (const float*)d_in[0];   // (8192, 4096) fp32
  const float* w = (const float*)d_in[1];   // (64, 2016) fp32
  float* out = (float*)d_out;               // (8192, 4096) fp32
  float* Rws = (float*)d_ws;                // 64*64*64 fp32 = 1 MB scratch

  oft_build_R<<<64, 256, 0, stream>>>(w, Rws);
  oft_apply<<<dim3(64, 32), 256, 0, stream>>>(x, Rws, out);
}

// Round 6
// 264.842 us; speedup vs baseline: 1.1608x; 1.0294x over previous
//
#include <hip/hip_runtime.h>

// OFT rotation: out[n, r*64+c] = sum_k x[n, r*64+k] * R[r][k][c]
// R[r] = I + 2(Q + 2Q^2-terms...), Q skew-symmetric from strict-upper weights.

#define BS 64
#define NW 2016   // 64*63/2
#define LDP 68    // padded LDS row stride (build_R only)

typedef float vf4 __attribute__((ext_vector_type(4)));  // nt-store-compatible float4

// ---------------- Kernel 1: build R (64 blocks, one per rotation block) -------------
// UNCHANGED: known-good, bit-exact vs reference (absmax 0.0).

__device__ __forceinline__ void mm_tile_68(const float (*A)[LDP], const float (*Bm)[LDP],
                                           int r0, int c0, float p[4][4]) {
  for (int k = 0; k < 64; k += 4) {
    float4 bv[4], av[4];
#pragma unroll
    for (int u = 0; u < 4; ++u) bv[u] = *(const float4*)&Bm[k + u][c0];
#pragma unroll
    for (int i = 0; i < 4; ++i) av[i] = *(const float4*)&A[r0 + i][k];
#pragma unroll
    for (int u = 0; u < 4; ++u) {
      const float4 b = bv[u];
#pragma unroll
      for (int i = 0; i < 4; ++i) {
        const float a = ((const float*)&av[i])[u];
        p[i][0] += a * b.x;
        p[i][1] += a * b.y;
        p[i][2] += a * b.z;
        p[i][3] += a * b.w;
      }
    }
  }
}

__global__ __launch_bounds__(256) void oft_build_R(const float* __restrict__ w,
                                                   float* __restrict__ Rout) {
  const int r = blockIdx.x;
  const int t = threadIdx.x;
  __shared__ float Q[BS][LDP];
  __shared__ float Pa[BS][LDP];
  __shared__ float Pb[BS][LDP];

  for (int f = t; f < BS * LDP; f += 256) (&Q[0][0])[f] = 0.f;
  __syncthreads();

  for (int i = t; i < NW; i += 256) {
    int row = 0, rem = i;
    while (rem >= 63 - row) { rem -= 63 - row; ++row; }
    const int col = row + 1 + rem;
    const float v = w[r * NW + i];
    Q[row][col] = v;
    Q[col][row] = -v;
  }
  __syncthreads();

  const int tr = t >> 4, tc = t & 15;
  const int r0 = tr * 4, c0 = tc * 4;

  float acc[4][4];
#pragma unroll
  for (int i = 0; i < 4; ++i)
#pragma unroll
    for (int j = 0; j < 4; ++j)
      acc[i][j] = ((r0 + i) == (c0 + j) ? 1.f : 0.f) + 2.f * Q[r0 + i][c0 + j];

  float p[4][4] = {};
  mm_tile_68(Q, Q, r0, c0, p);
#pragma unroll
  for (int i = 0; i < 4; ++i)
#pragma unroll
    for (int j = 0; j < 4; ++j) {
      Pa[r0 + i][c0 + j] = p[i][j];
      acc[i][j] += 2.f * p[i][j];
    }
  __syncthreads();

  float p2[4][4] = {};
  mm_tile_68(Pa, Q, r0, c0, p2);
#pragma unroll
  for (int i = 0; i < 4; ++i)
#pragma unroll
    for (int j = 0; j < 4; ++j) {
      Pb[r0 + i][c0 + j] = p2[i][j];
      acc[i][j] += 2.f * p2[i][j];
    }
  __syncthreads();

  float p3[4][4] = {};
  mm_tile_68(Pb, Q, r0, c0, p3);
#pragma unroll
  for (int i = 0; i < 4; ++i)
#pragma unroll
    for (int j = 0; j < 4; ++j)
      acc[i][j] += 2.f * p3[i][j];

#pragma unroll
  for (int i = 0; i < 4; ++i) {
    float4 v = make_float4(acc[i][0], acc[i][1], acc[i][2], acc[i][3]);
    *(float4*)&Rout[(size_t)r * 4096 + (size_t)(r0 + i) * 64 + c0] = v;
  }
}

// ---------------- Kernel 2: apply rotation (v6: 8x8 tile + dbuf + full VGPR) --------
//
// v5 (103us) diagnosis: VGPR capped at 88 by default launch bounds -> compiler
// serialized load/FMA chunks (128 cyc compute vs ~120 cyc ds latency, 2 waves/SIMD)
// -> ~2x latency stall. Also epilogue wrote 16B-at-32B-stride -> WRITE_SIZE 139MB.
// v6: __launch_bounds__(256,2) (occupancy is LDS-capped at 2 waves/SIMD anyway, so
// free VGPRs), explicit k double-buffer (16 loads in flight across 512 FMA issue
// cycles), contiguous-column store map (cols tc*4 and 32+tc*4).
// Model: LDS reads heavily deduped (A 8-way, B 8-way broadcast) ~15-20us; VALU
// floor 27us; HBM 42us with overlap -> expect ~50us.
// k ascending single fmaf chain per output -> bit-identical to reference.

__device__ __forceinline__ void load_frag(const float* __restrict__ Xw,
                                          const float* __restrict__ Rs,
                                          int kbase, int m, int tr, int tc,
                                          float4 A[4][2], float4 B[4][2]) {
  // (kbase+u)&7 == m+u for kbase%8==0 (m=0) or %8==4 (m=4): compile-time swizzle.
#pragma unroll
  for (int u = 0; u < 4; ++u) {
    const int k = kbase + u;
    const int s0 = ((2 * tr + 0) ^ (m + u)) * 4;
    const int s1 = ((2 * tr + 1) ^ (m + u)) * 4;
    A[u][0] = *(const float4*)&Xw[k * 64 + s0];
    A[u][1] = *(const float4*)&Xw[k * 64 + s1];
    B[u][0] = *(const float4*)&Rs[k * 64 + tc * 4];
    B[u][1] = *(const float4*)&Rs[k * 64 + 32 + tc * 4];
  }
}

__device__ __forceinline__ void fma_frag(const float4 A[4][2], const float4 B[4][2],
                                         float acc[8][8]) {
#pragma unroll
  for (int u = 0; u < 4; ++u) {
    const float av[8] = {A[u][0].x, A[u][0].y, A[u][0].z, A[u][0].w,
                         A[u][1].x, A[u][1].y, A[u][1].z, A[u][1].w};
    const float bv[8] = {B[u][0].x, B[u][0].y, B[u][0].z, B[u][0].w,
                         B[u][1].x, B[u][1].y, B[u][1].z, B[u][1].w};
#pragma unroll
    for (int i = 0; i < 8; ++i)
#pragma unroll
      for (int j = 0; j < 8; ++j)
        acc[i][j] = fmaf(av[i], bv[j], acc[i][j]);
  }
}

__global__ __launch_bounds__(256, 2) void oft_apply(const float* __restrict__ x,
                                                    const float* __restrict__ R,
                                                    float* __restrict__ out) {
  const int r = blockIdx.x;      // rotation block 0..63
  const int tile = blockIdx.y;   // 256-row tile 0..31
  const int t = threadIdx.x;
  const int lane = t & 63;
  const int wv = t >> 6;         // wave 0..3, owns rows [wv*64, wv*64+64)

  __shared__ float Rs[64 * 64];      // 16 KB, flat row-major
  __shared__ float Xt[4][64 * 64];   // 4 x 16 KB, per-wave TRANSPOSED x (k-major)

  const int n0 = tile * 256 + wv * 64;

  // ---- stage Rs: whole block, coalesced b128 ----
  {
    const float4* Rg = (const float4*)(R + (size_t)r * 4096);
    float4* Rs4 = (float4*)Rs;
#pragma unroll
    for (int i = 0; i < 4; ++i) Rs4[t + 256 * i] = Rg[t + 256 * i];
  }

  // ---- stage Xt[wv]: 64 rows x 64 k, transposed + quad-swizzled ----
  float* __restrict__ Xw = &Xt[wv][0];
  {
    const int rq = lane >> 2;        // row-quad 0..15
    const int kq0 = lane & 3;        // k-quad sub-index
    const float* xg = x + (size_t)n0 * 4096 + (size_t)r * 64;
#pragma unroll
    for (int i = 0; i < 4; ++i) {
      const int kq = kq0 + 4 * i;    // k-quad 0..15
      const float4 v0 = *(const float4*)&xg[(size_t)(rq * 4 + 0) * 4096 + kq * 4];
      const float4 v1 = *(const float4*)&xg[(size_t)(rq * 4 + 1) * 4096 + kq * 4];
      const float4 v2 = *(const float4*)&xg[(size_t)(rq * 4 + 2) * 4096 + kq * 4];
      const float4 v3 = *(const float4*)&xg[(size_t)(rq * 4 + 3) * 4096 + kq * 4];
      // 4x4 transpose in registers: w_c[d] = x[rq*4+d][kq*4+c]
      const float4 w0 = make_float4(v0.x, v1.x, v2.x, v3.x);
      const float4 w1 = make_float4(v0.y, v1.y, v2.y, v3.y);
      const float4 w2 = make_float4(v0.z, v1.z, v2.z, v3.z);
      const float4 w3 = make_float4(v0.w, v1.w, v2.w, v3.w);
#pragma unroll
      for (int c = 0; c < 4; ++c) {
        const int k = kq * 4 + c;
        const int slot = rq ^ (k & 7);           // quad swizzle
        const float4 wc = (c == 0) ? w0 : (c == 1) ? w1 : (c == 2) ? w2 : w3;
        *(float4*)&Xw[k * 64 + slot * 4] = wc;
      }
    }
  }
  __syncthreads();   // Rs (block-shared) ready; Xt is wave-private (in-order DS)

  // ---- main loop: 8x8 per-thread tile, double-buffered over k ----
  const int tr = lane >> 3;   // thread-row 0..7 -> rows tr*8..tr*8+7
  const int tc = lane & 7;    // thread-col: cols tc*4..+3 and 32+tc*4..+3

  float acc[8][8];
#pragma unroll
  for (int i = 0; i < 8; ++i)
#pragma unroll
    for (int j = 0; j < 8; ++j) acc[i][j] = 0.f;

  float4 a0[4][2], b0[4][2], a1[4][2], b1[4][2];
  load_frag(Xw, Rs, 0, 0, tr, tc, a0, b0);
  for (int k0 = 0; k0 < 64; k0 += 8) {
    load_frag(Xw, Rs, k0 + 4, 4, tr, tc, a1, b1);   // prefetch while computing
    fma_frag(a0, b0, acc);
    if (k0 + 8 < 64) load_frag(Xw, Rs, k0 + 8, 0, tr, tc, a0, b0);
    fma_frag(a1, b1, acc);
  }

  // ---- epilogue: contiguous-column nt stores ----
  // per instr: 8 rows x 8 lanes x 16 B contiguous (cols tc*4 / 32+tc*4): full lines.
  float* __restrict__ og = out + (size_t)(n0 + tr * 8) * 4096 + (size_t)r * 64;
#pragma unroll
  for (int i = 0; i < 8; ++i) {
    vf4 lo, hi;
    lo.x = acc[i][0]; lo.y = acc[i][1]; lo.z = acc[i][2]; lo.w = acc[i][3];
    hi.x = acc[i][4]; hi.y = acc[i][5]; hi.z = acc[i][6]; hi.w = acc[i][7];
    __builtin_nontemporal_store(lo, (vf4*)&og[(size_t)i * 4096 + tc * 4]);
    __builtin_nontemporal_store(hi, (vf4*)&og[(size_t)i * 4096 + 32 + tc * 4]);
  }
}

extern "C" void kernel_launch(void* const* d_in, const int* in_sizes, int n_in,
                              void* d_out, int out_size, void* d_ws, size_t ws_size,
                              hipStream_t stream) {
  const float* x = (const float*)d_in[0];   // (8192, 4096) fp32
  const float* w = (const float*)d_in[1];   // (64, 2016) fp32
  float* out = (float*)d_out;               // (8192, 4096) fp32
  float* Rws = (float*)d_ws;                // 64*64*64 fp32 = 1 MB scratch

  oft_build_R<<<64, 256, 0, stream>>>(w, Rws);
  oft_apply<<<dim3(64, 32), 256, 0, stream>>>(x, Rws, out);
}